// Round 4
// baseline (69.982 us; speedup 1.0000x reference)
//
#include <hip/hip_runtime.h>
#include <hip/hip_bf16.h>

// Causal conv1d as bf16 32x32x16-MFMA batched GEMM, double-buffered BK=16.
// out[b,h,t] = sum_{c,k} x[b,c,t+k-3] * W[h, c*4+k] + bias[h]
// B=8, C=256, T=4096, H=512, K=4

#define Bb 8
#define Cc 256
#define Tt 4096
#define Hh 512
#define Kk 4

typedef __attribute__((ext_vector_type(8)))  short bf16x8;
typedef __attribute__((ext_vector_type(16))) float f32x16;

// ---------------- workspace layout ----------------
#define WS_XT_OFF   0
#define WS_WT_OFF   16777216
#define WS_ZERO_OFF 17825792
#define WS_NEEDED   17826816ULL   // + 1KB zero page

__device__ __forceinline__ void gload16(const void* g, void* l) {
    __builtin_amdgcn_global_load_lds(
        (const __attribute__((address_space(1))) void*)g,
        (__attribute__((address_space(3))) void*)l, 16, 0, 0);
}

// ---------- prep 1: W[h, c*4+k] f32 -> Wt[k][h][c] bf16, + 1KB zero page ----------
__global__ __launch_bounds__(256) void wt_prep_kernel(const float* __restrict__ W,
                                                      __hip_bfloat16* __restrict__ Wt,
                                                      float* __restrict__ zeros) {
    int n = blockIdx.x * 256 + threadIdx.x;           // [0, 4*512*256)
    int c = n & 255;
    int h = (n >> 8) & 511;
    int k = n >> 17;
    Wt[n] = __float2bfloat16(W[h * (Cc * Kk) + c * Kk + k]);
    if (blockIdx.x == 0) zeros[threadIdx.x] = 0.f;    // 256 floats = 1 KB
}

// ---------- prep 2: x[b][c][t] f32 -> xT[b][t][c] bf16 (LDS tile transpose) ----------
__global__ __launch_bounds__(256) void xt_prep_kernel(const float* __restrict__ x,
                                                      __hip_bfloat16* __restrict__ xT) {
    __shared__ __hip_bfloat16 tile[64][66];           // +2 pad
    const int t0 = blockIdx.x * 64, c0 = blockIdx.y * 64, b = blockIdx.z;
    const int lt = threadIdx.x & 63, lw = threadIdx.x >> 6;
#pragma unroll
    for (int i = 0; i < 16; ++i) {
        int cc = lw + i * 4;
        tile[cc][lt] = __float2bfloat16(x[((size_t)(b * Cc + c0 + cc)) * Tt + t0 + lt]);
    }
    __syncthreads();
#pragma unroll
    for (int i = 0; i < 16; ++i) {
        int tt = lw + i * 4;
        xT[((size_t)(b * Tt + t0 + tt)) * Cc + c0 + lt] = tile[lt][tt];
    }
}

// ---------- main: 128h x 128t tile, 4 waves (2x2 of 64x64), BK=16, dbuf ----------
// Buffer: A [k4][h128][ks2][16B] = 16384 B ; B [t256pad][ks2][16B] = 8192 B.
// Frag reads are permuted-contiguous 1024 B per wave -> bank-ideal (m134 pattern).
#define BK        16
#define NSTEPS    (Cc / BK)      // 16
#define A_BYTES   16384
#define BUF_BYTES 24576          // A + B(8192); x2 buffers = 49152 -> 3 blocks/CU

__global__ __launch_bounds__(256, 3) void conv_mfma_kernel(
    const __hip_bfloat16* __restrict__ xT,
    const __hip_bfloat16* __restrict__ Wt,
    const float* __restrict__ bias,
    const float* __restrict__ zeros,
    float* __restrict__ out)
{
    __shared__ __align__(1024) char smem[2 * BUF_BYTES];
    const int tid  = threadIdx.x;
    const int lane = tid & 63;
    const int wave = tid >> 6;
    const int wr = wave >> 1, wc = wave & 1;          // 2x2 wave grid (h, t)
    const int l31 = lane & 31, lh = lane >> 5;

    // bijective XCD-chunked swizzle (1024 blocks % 8 == 0)
    const int flat = blockIdx.x + 32 * (blockIdx.y + 4 * blockIdx.z);
    const int nf   = (flat & 7) * 128 + (flat >> 3);
    const int t0 = (nf & 31) * 128;
    const int h0 = ((nf >> 5) & 3) * 128;
    const int b  = nf >> 7;

    // ---- staging descriptors (slot-linear dst; sources advance +32B/step) ----
    const char* asrc[4]; int adst[4];
#pragma unroll
    for (int i = 0; i < 4; ++i) {
        int s = tid + i * 256;                        // 0..1023
        int k = s >> 8, h = (s >> 1) & 127, ks = s & 1;
        asrc[i] = (const char*)Wt + (((size_t)(k * Hh + h0 + h)) * Cc + ks * 8) * 2;
        adst[i] = s * 16;
    }
    const char* bsrc[2]; int bdst[2];
#pragma unroll
    for (int i = 0; i < 2; ++i) {
        int s = tid + i * 256;                        // 0..511 ; rows 0..130 real
        int t = s >> 1, ks = s & 1;
        int tg = t0 - 3 + t;
        bool valid = (t <= 130) && (tg >= 0);
        bsrc[i] = valid ? (const char*)xT + (((size_t)(b * Tt + tg)) * Cc + ks * 8) * 2
                        : (const char*)zeros;
        bdst[i] = A_BYTES + s * 16;
    }

    // frag read offsets (per-lane; contiguous 1024B per 64-lane wave)
    const int aoff = wr * 2048 + l31 * 32 + lh * 16;            // + k*4096 + i*1024
    const int boff = A_BYTES + wc * 2048 + l31 * 32 + lh * 16;  // + j*1024 + k*32

    f32x16 acc[2][2] = {};

    // ---- prologue: stage buffer 0 ----
#pragma unroll
    for (int i = 0; i < 4; ++i) { gload16(asrc[i], smem + adst[i]); asrc[i] += BK * 2; }
#pragma unroll
    for (int i = 0; i < 2; ++i) { gload16(bsrc[i], smem + bdst[i]); bsrc[i] += BK * 2; }
    __syncthreads();

    int cur = 0;
    for (int s = 0; s < NSTEPS; ++s) {
        const char* bufp = smem + cur * BUF_BYTES;
        char* nxtp = smem + (cur ^ 1) * BUF_BYTES;
        if (s < NSTEPS - 1) {
#pragma unroll
            for (int i = 0; i < 4; ++i) { gload16(asrc[i], nxtp + adst[i]); asrc[i] += BK * 2; }
#pragma unroll
            for (int i = 0; i < 2; ++i) { gload16(bsrc[i], nxtp + bdst[i]); bsrc[i] += BK * 2; }
        }
#pragma unroll
        for (int k = 0; k < 4; ++k) {
            bf16x8 a0 = *(const bf16x8*)(bufp + k * 4096 + aoff);
            bf16x8 a1 = *(const bf16x8*)(bufp + k * 4096 + 1024 + aoff);
            bf16x8 b0 = *(const bf16x8*)(bufp + boff + k * 32);          // t_local + k shift
            bf16x8 b1 = *(const bf16x8*)(bufp + boff + 1024 + k * 32);
            acc[0][0] = __builtin_amdgcn_mfma_f32_32x32x16_bf16(a0, b0, acc[0][0], 0, 0, 0);
            acc[0][1] = __builtin_amdgcn_mfma_f32_32x32x16_bf16(a0, b1, acc[0][1], 0, 0, 0);
            acc[1][0] = __builtin_amdgcn_mfma_f32_32x32x16_bf16(a1, b0, acc[1][0], 0, 0, 0);
            acc[1][1] = __builtin_amdgcn_mfma_f32_32x32x16_bf16(a1, b1, acc[1][1], 0, 0, 0);
        }
        __syncthreads();   // drains vmcnt (next buffer landed) + frees cur for restage
        cur ^= 1;
    }

    // ---- epilogue: 32x32 D layout: col=lane&31 -> t, row=(r&3)+8*(r>>2)+4*(lane>>5) -> h ----
#pragma unroll
    for (int i = 0; i < 2; ++i) {
#pragma unroll
        for (int j = 0; j < 2; ++j) {
#pragma unroll
            for (int r = 0; r < 16; ++r) {
                int hl = (r & 3) + 8 * (r >> 2) + 4 * lh;
                int h  = h0 + wr * 64 + i * 32 + hl;
                int t  = t0 + wc * 64 + j * 32 + l31;
                out[((size_t)(b * Hh + h)) * Tt + t] = acc[i][j][r] + bias[h];
            }
        }
    }
}

// ---------------- fallback (ws too small): fp32 kernel ----------------
#define TT 256
#define HT 8
#define CT 4
__global__ __launch_bounds__(256) void conv1d_f32_kernel(
    const float* __restrict__ x, const float* __restrict__ W,
    const float* __restrict__ bias, float* __restrict__ out)
{
    const int tid = threadIdx.x;
    const int t0 = blockIdx.x * TT;
    const int h0 = blockIdx.y * HT;
    const int b  = blockIdx.z;
    __shared__ float xs[CT][TT + Kk];
    float acc[HT];
#pragma unroll
    for (int h = 0; h < HT; ++h) acc[h] = 0.f;
    const float* xb = x + (size_t)b * Cc * Tt;
    for (int c0 = 0; c0 < Cc; c0 += CT) {
        __syncthreads();
#pragma unroll
        for (int cc = 0; cc < CT; ++cc)
            for (int j = tid; j < TT + Kk - 1; j += 256) {
                int idx = t0 - (Kk - 1) + j;
                xs[cc][j] = (idx >= 0) ? xb[(size_t)(c0 + cc) * Tt + idx] : 0.f;
            }
        __syncthreads();
#pragma unroll
        for (int cc = 0; cc < CT; ++cc) {
            float xv[Kk];
#pragma unroll
            for (int k = 0; k < Kk; ++k) xv[k] = xs[cc][tid + k];
#pragma unroll
            for (int h = 0; h < HT; ++h) {
                const float* wp = W + (size_t)(h0 + h) * (Cc * Kk) + (size_t)(c0 + cc) * Kk;
#pragma unroll
                for (int k = 0; k < Kk; ++k) acc[h] += wp[k] * xv[k];
            }
        }
    }
#pragma unroll
    for (int h = 0; h < HT; ++h)
        out[((size_t)b * Hh + (h0 + h)) * Tt + t0 + tid] = acc[h] + bias[h0 + h];
}

extern "C" void kernel_launch(void* const* d_in, const int* in_sizes, int n_in,
                              void* d_out, int out_size, void* d_ws, size_t ws_size,
                              hipStream_t stream) {
    const float* x    = (const float*)d_in[0];
    const float* W    = (const float*)d_in[1];
    const float* bias = (const float*)d_in[2];
    float* out        = (float*)d_out;

    if (ws_size >= WS_NEEDED) {
        __hip_bfloat16* xT = (__hip_bfloat16*)((char*)d_ws + WS_XT_OFF);
        __hip_bfloat16* Wt = (__hip_bfloat16*)((char*)d_ws + WS_WT_OFF);
        float* zeros       = (float*)((char*)d_ws + WS_ZERO_OFF);

        wt_prep_kernel<<<dim3((Kk * Hh * Cc) / 256), dim3(256), 0, stream>>>(W, Wt, zeros);
        xt_prep_kernel<<<dim3(Tt / 64, Cc / 64, Bb), dim3(256), 0, stream>>>(x, xT);
        conv_mfma_kernel<<<dim3(Tt / 128, Hh / 128, Bb), dim3(256), 0, stream>>>(xT, Wt, bias, zeros, out);
    } else {
        conv1d_f32_kernel<<<dim3(Tt / TT, Hh / HT, Bb), dim3(256), 0, stream>>>(x, W, bias, out);
    }
}

// Round 5
// 66.848 us; speedup vs baseline: 1.0469x; 1.0469x over previous
//
#include <hip/hip_runtime.h>
#include <hip/hip_bf16.h>

// Causal conv1d as bf16 MFMA GEMM. m201-style counted-vmcnt pipeline,
// 3 LDS buffers (race-free stage kt+2 during kt), XOR-swizzled tiles.
// out[b,h,t] = sum_{c,k} x[b,c,t+k-3] * W[h, c*4+k] + bias[h]
// B=8, C=256, T=4096, H=512, K=4. GEMM-K = k-major (k*256 + c).

#define Bb 8
#define Cc 256
#define Tt 4096
#define Hh 512
#define Kk 4

typedef __attribute__((ext_vector_type(8)))  short bf16x8;
typedef __attribute__((ext_vector_type(16))) float f32x16;

#define WS_XT_OFF   0
#define WS_WT_OFF   16777216
#define WS_ZERO_OFF 17825792
#define WS_NEEDED   17826816ULL

__device__ __forceinline__ void gload16(const void* g, void* l) {
    __builtin_amdgcn_global_load_lds(
        (const __attribute__((address_space(1))) void*)g,
        (__attribute__((address_space(3))) void*)l, 16, 0, 0);
}

// ---------- prep 1: W[h, c*4+k] f32 -> Wt[k][h][c] bf16, + 1KB zero page ----------
__global__ __launch_bounds__(256) void wt_prep_kernel(const float* __restrict__ W,
                                                      __hip_bfloat16* __restrict__ Wt,
                                                      float* __restrict__ zeros) {
    int n = blockIdx.x * 256 + threadIdx.x;           // [0, 4*512*256)
    int c = n & 255;
    int h = (n >> 8) & 511;
    int k = n >> 17;
    Wt[n] = __float2bfloat16(W[h * (Cc * Kk) + c * Kk + k]);
    if (blockIdx.x == 0) zeros[threadIdx.x] = 0.f;    // 1 KB zero page
}

// ---------- prep 2: x[b][c][t] f32 -> xT[b][t][c] bf16, 16B vector stores ----------
__global__ __launch_bounds__(256) void xt_prep_kernel(const float* __restrict__ x,
                                                      __hip_bfloat16* __restrict__ xT) {
    __shared__ __hip_bfloat16 tile[64][72];           // +8 pad: spread column reads
    const int t0 = blockIdx.x * 64, c0 = blockIdx.y * 64, b = blockIdx.z;
    const int lt = threadIdx.x & 63, lw = threadIdx.x >> 6;
#pragma unroll
    for (int i = 0; i < 16; ++i) {
        int cc = lw + i * 4;
        tile[cc][lt] = __float2bfloat16(x[((size_t)(b * Cc + c0 + cc)) * Tt + t0 + lt]);
    }
    __syncthreads();
#pragma unroll
    for (int i = 0; i < 2; ++i) {
        int tt = (threadIdx.x >> 3) + i * 32;
        int c8 = threadIdx.x & 7;
        short tmp[8];
#pragma unroll
        for (int j = 0; j < 8; ++j) {
            __hip_bfloat16 v = tile[c8 * 8 + j][tt];
            tmp[j] = *reinterpret_cast<short*>(&v);
        }
        *reinterpret_cast<bf16x8*>(&xT[((size_t)(b * Tt + t0 + tt)) * Cc + c0 + c8 * 8]) =
            *reinterpret_cast<bf16x8*>(tmp);
    }
}

// ---------- main: BM=256(h) x BN=128(t), BK=64, 8 waves (4Mx2N, 64x64/wave) ----------
// Per buffer: A [256 rows][128B] = 32768, B [128 rows][128B] = 16384 -> 48 KB.
// Swizzle (both tiles): phys_byte(row, o) = row*128 + (o ^ ((row&7)<<4)).
#define A_BYTES   32768
#define BUF_BYTES 49152
#define NKT       16          // 4 kc * 4 c-chunks of 64

// stage K-tile kt_ into buffer kt_%3 (A: 4 loads, B: 2 loads per thread)
#define STAGE(kt_) do {                                                                     \
    const int kc_ = (kt_) >> 2, cj_ = (kt_) & 3;                                            \
    char* bb_ = smem + ((kt_) % 3) * BUF_BYTES;                                             \
    _Pragma("unroll") for (int i = 0; i < 4; ++i)                                           \
        gload16(asrc[i] + kc_ * (Hh * Cc * 2) + cj_ * 128, bb_ + adst[i]);                  \
    _Pragma("unroll") for (int i = 0; i < 2; ++i) {                                         \
        const char* s_ = (btg[i] + kc_ >= 0)                                                \
            ? xT_c + boff[i] + kc_ * (Cc * 2) + cj_ * 128 : bz[i];                          \
        gload16(s_, bb_ + bdst[i]);                                                         \
    }                                                                                       \
} while (0)

__global__ __launch_bounds__(512, 1) void conv_mfma_kernel(
    const __hip_bfloat16* __restrict__ xT,
    const __hip_bfloat16* __restrict__ Wt,
    const float* __restrict__ bias,
    const float* __restrict__ zeros,
    float* __restrict__ out)
{
    __shared__ __align__(1024) char smem[3 * BUF_BYTES];   // 147456 B
    const int tid  = threadIdx.x;
    const int lane = tid & 63;
    const int wave = tid >> 6;
    const int wr = wave >> 1, wc = wave & 1;     // 4(M h) x 2(N t)
    const int l31 = lane & 31, lh = lane >> 5;

    // XCD swizzle: 512 blocks, XCD x gets batch x (2MB xT slice -> L2-resident)
    const int flat = blockIdx.x + 32 * blockIdx.y + 64 * blockIdx.z;
    const int swz  = (flat & 7) * 64 + (flat >> 3);
    const int t0 = (swz & 31) * 128;
    const int h0 = ((swz >> 5) & 1) * 256;
    const int b  = swz >> 6;

    const char* xT_c = (const char*)xT;
    const char* Wt_c = (const char*)Wt;

    // ---- staging descriptors (linear LDS dst; inverse-swizzled global src) ----
    const char* asrc[4]; int adst[4];
#pragma unroll
    for (int i = 0; i < 4; ++i) {
        int s = tid + i * 512;                   // 0..2047
        int row = s >> 3, sl = s & 7;
        int clog = ((sl ^ (row & 7)) << 3);      // bf16 col
        asrc[i] = Wt_c + (((size_t)(h0 + row)) * Cc + clog) * 2;
        adst[i] = s * 16;
    }
    long long boff[2]; int bdst[2]; int btg[2]; const char* bz[2];
#pragma unroll
    for (int i = 0; i < 2; ++i) {
        int s = tid + i * 512;                   // 0..1023
        int r = s >> 3, sl = s & 7;
        int clog = ((sl ^ (r & 7)) << 3);
        btg[i]  = t0 - 3 + r;                    // + kc at stage time
        boff[i] = (((long long)b * Tt + btg[i]) * Cc + clog) * 2;
        bdst[i] = A_BYTES + s * 16;
        bz[i]   = (const char*)zeros + (s & 63) * 16;
    }

    // ---- fragment read offsets (swizzled) ----
    const int xorv = (lane & 7) << 4;
    int soff[4];
#pragma unroll
    for (int ks = 0; ks < 4; ++ks) soff[ks] = (ks * 32 + lh * 16) ^ xorv;
    const int aoffb = (wr * 64 + l31) * 128;              // + fm*4096 + soff[ks]
    const int boffb = A_BYTES + (wc * 64 + l31) * 128;    // + ft*4096 + soff[ks]

    f32x16 acc[2][2] = {};

    // ---- prologue: stage kt 0,1; wait kt0 landed; barrier ----
    STAGE(0);
    STAGE(1);
    asm volatile("s_waitcnt vmcnt(6)" ::: "memory");
    __builtin_amdgcn_s_barrier();

    // ---- main loop ----
#pragma unroll
    for (int kt = 0; kt < NKT; ++kt) {
        const char* bufp = smem + (kt % 3) * BUF_BYTES;
        bf16x8 a[2][4], bv[2][4];
#pragma unroll
        for (int fm = 0; fm < 2; ++fm)
#pragma unroll
            for (int ks = 0; ks < 4; ++ks)
                a[fm][ks] = *(const bf16x8*)(bufp + aoffb + fm * 4096 + soff[ks]);
#pragma unroll
        for (int ft = 0; ft < 2; ++ft)
#pragma unroll
            for (int ks = 0; ks < 4; ++ks)
                bv[ft][ks] = *(const bf16x8*)(bufp + boffb + ft * 4096 + soff[ks]);

        if (kt < NKT - 2) STAGE(kt + 2);

        __builtin_amdgcn_s_setprio(1);
#pragma unroll
        for (int ks = 0; ks < 4; ++ks)
#pragma unroll
            for (int fm = 0; fm < 2; ++fm)
#pragma unroll
                for (int ft = 0; ft < 2; ++ft)
                    acc[fm][ft] = __builtin_amdgcn_mfma_f32_32x32x16_bf16(
                        a[fm][ks], bv[ft][ks], acc[fm][ft], 0, 0, 0);
        __builtin_amdgcn_s_setprio(0);

        if (kt < NKT - 2)       asm volatile("s_waitcnt vmcnt(6)" ::: "memory");
        else if (kt == NKT - 2) asm volatile("s_waitcnt vmcnt(0)" ::: "memory");
        if (kt < NKT - 1) __builtin_amdgcn_s_barrier();
    }

    // ---- epilogue: D col=lane&31 -> t, row=(r&3)+8*(r>>2)+4*lh -> h ----
#pragma unroll
    for (int fm = 0; fm < 2; ++fm)
#pragma unroll
        for (int ft = 0; ft < 2; ++ft)
#pragma unroll
            for (int r = 0; r < 16; ++r) {
                int h = h0 + wr * 64 + fm * 32 + (r & 3) + 8 * (r >> 2) + 4 * lh;
                int t = t0 + wc * 64 + ft * 32 + l31;
                out[((size_t)(b * Hh + h)) * Tt + t] = acc[fm][ft][r] + bias[h];
            }
}

// ---------------- fallback (ws too small): fp32 kernel ----------------
#define TT 256
#define HT 8
#define CT 4
__global__ __launch_bounds__(256) void conv1d_f32_kernel(
    const float* __restrict__ x, const float* __restrict__ W,
    const float* __restrict__ bias, float* __restrict__ out)
{
    const int tid = threadIdx.x;
    const int t0 = blockIdx.x * TT;
    const int h0 = blockIdx.y * HT;
    const int b  = blockIdx.z;
    __shared__ float xs[CT][TT + Kk];
    float acc[HT];
#pragma unroll
    for (int h = 0; h < HT; ++h) acc[h] = 0.f;
    const float* xb = x + (size_t)b * Cc * Tt;
    for (int c0 = 0; c0 < Cc; c0 += CT) {
        __syncthreads();
#pragma unroll
        for (int cc = 0; cc < CT; ++cc)
            for (int j = tid; j < TT + Kk - 1; j += 256) {
                int idx = t0 - (Kk - 1) + j;
                xs[cc][j] = (idx >= 0) ? xb[(size_t)(c0 + cc) * Tt + idx] : 0.f;
            }
        __syncthreads();
#pragma unroll
        for (int cc = 0; cc < CT; ++cc) {
            float xv[Kk];
#pragma unroll
            for (int k = 0; k < Kk; ++k) xv[k] = xs[cc][tid + k];
#pragma unroll
            for (int h = 0; h < HT; ++h) {
                const float* wp = W + (size_t)(h0 + h) * (Cc * Kk) + (size_t)(c0 + cc) * Kk;
#pragma unroll
                for (int k = 0; k < Kk; ++k) acc[h] += wp[k] * xv[k];
            }
        }
    }
#pragma unroll
    for (int h = 0; h < HT; ++h)
        out[((size_t)b * Hh + (h0 + h)) * Tt + t0 + tid] = acc[h] + bias[h0 + h];
}

extern "C" void kernel_launch(void* const* d_in, const int* in_sizes, int n_in,
                              void* d_out, int out_size, void* d_ws, size_t ws_size,
                              hipStream_t stream) {
    const float* x    = (const float*)d_in[0];
    const float* W    = (const float*)d_in[1];
    const float* bias = (const float*)d_in[2];
    float* out        = (float*)d_out;

    if (ws_size >= WS_NEEDED) {
        __hip_bfloat16* xT = (__hip_bfloat16*)((char*)d_ws + WS_XT_OFF);
        __hip_bfloat16* Wt = (__hip_bfloat16*)((char*)d_ws + WS_WT_OFF);
        float* zeros       = (float*)((char*)d_ws + WS_ZERO_OFF);

        wt_prep_kernel<<<dim3((Kk * Hh * Cc) / 256), dim3(256), 0, stream>>>(W, Wt, zeros);
        xt_prep_kernel<<<dim3(Tt / 64, Cc / 64, Bb), dim3(256), 0, stream>>>(x, xT);
        conv_mfma_kernel<<<dim3(32, 2, 8), dim3(512), 0, stream>>>(xT, Wt, bias, zeros, out);
    } else {
        conv1d_f32_kernel<<<dim3(Tt / TT, Hh / HT, Bb), dim3(256), 0, stream>>>(x, W, bias, out);
    }
}

// Round 6
// 50.666 us; speedup vs baseline: 1.3812x; 1.3194x over previous
//
#include <hip/hip_runtime.h>
#include <hip/hip_bf16.h>

// Causal conv1d as bf16 MFMA GEMM — faithful m201 8-phase port.
// out[b,h,t] = sum_{c,k} x[b,c,t+k-3] * W[h, c*4+k] + bias[h]
// B=8, C=256, T=4096, H=512, K=4.

#define Bb 8
#define Cc 256
#define Tt 4096
#define Hh 512
#define Kk 4

typedef __attribute__((ext_vector_type(8))) short bf16x8;
typedef __attribute__((ext_vector_type(4))) float f32x4;

#define WS_XT_OFF   0
#define WS_WT_OFF   16777216
#define WS_ZERO_OFF 17825792
#define WS_NEEDED   17826816ULL

__device__ __forceinline__ void gload16(const void* g, void* l) {
    __builtin_amdgcn_global_load_lds(
        (const __attribute__((address_space(1))) void*)g,
        (__attribute__((address_space(3))) void*)l, 16, 0, 0);
}

// ---------- merged prep: xT transpose (blocks 0..2047) + Wt pack (2048..4095) ----------
__global__ __launch_bounds__(256) void prep_kernel(const float* __restrict__ x,
                                                   const float* __restrict__ W,
                                                   __hip_bfloat16* __restrict__ xT,
                                                   __hip_bfloat16* __restrict__ Wt,
                                                   float* __restrict__ zeros) {
    __shared__ __hip_bfloat16 tile[64][72];
    const int bid = blockIdx.x;
    if (bid < 2048) {
        const int t0 = (bid & 63) * 64, c0 = ((bid >> 6) & 3) * 64, b = bid >> 8;
        const int lt = threadIdx.x & 63, lw = threadIdx.x >> 6;
#pragma unroll
        for (int i = 0; i < 16; ++i) {
            int cc = lw + i * 4;
            tile[cc][lt] = __float2bfloat16(x[((size_t)(b * Cc + c0 + cc)) * Tt + t0 + lt]);
        }
        __syncthreads();
#pragma unroll
        for (int i = 0; i < 2; ++i) {
            int tt = (threadIdx.x >> 3) + i * 32;
            int c8 = threadIdx.x & 7;
            short tmp[8];
#pragma unroll
            for (int j = 0; j < 8; ++j) {
                __hip_bfloat16 v = tile[c8 * 8 + j][tt];
                tmp[j] = *reinterpret_cast<short*>(&v);
            }
            *reinterpret_cast<bf16x8*>(&xT[((size_t)(b * Tt + t0 + tt)) * Cc + c0 + c8 * 8]) =
                *reinterpret_cast<bf16x8*>(tmp);
        }
    } else {
        int n = (bid - 2048) * 256 + threadIdx.x;     // [0, 4*512*256)
        int c = n & 255;
        int h = (n >> 8) & 511;
        int k = n >> 17;
        Wt[n] = __float2bfloat16(W[h * (Cc * Kk) + c * Kk + k]);
        if (bid == 2048) zeros[threadIdx.x] = 0.f;    // 1 KB zero page
    }
}

// ---------- main: BM=256h x BN=256t, 8 waves (2Mx4N -> 128x64/wave), 16x16x32 ----------
// K-step = 2 conv-k x 32 ch (GEMM-K 64); 16 steps; 4 phases/step (m201 template).
// A: 3 bufs x [2kk][256h][4 slots x 16B] = 3 x 32768. B: 2 bufs x [272 t-rows][4 x 16B].
// Swizzle: slot_phys = slot_logical ^ ((row>>1)&3)  -> frag reads 2-way bank aliasing (free).
#define A_STRIDE 32768
#define B_BASE   98304
#define B_STRIDE 17408
#define LDS_TOTAL 133120

#define BAR __builtin_amdgcn_s_barrier()
#define LGKM0 do { asm volatile("s_waitcnt lgkmcnt(0)" ::: "memory"); \
                   __builtin_amdgcn_sched_barrier(0); } while (0)

__global__ __launch_bounds__(512, 1) void conv_mfma_kernel(
    const __hip_bfloat16* __restrict__ xT,
    const __hip_bfloat16* __restrict__ Wt,
    const float* __restrict__ bias,
    const float* __restrict__ zeros,
    float* __restrict__ out)
{
    __shared__ __align__(1024) char smem[LDS_TOTAL];
    const int tid = threadIdx.x, lane = tid & 63, wave = tid >> 6;
    const int wr = wave >> 2, wc = wave & 3;          // 2(M h) x 4(N t)
    const int l15 = lane & 15, lg = lane >> 4;

    // XCD swizzle: 256 blocks, XCD x gets batch x (2MB xT slice L2-resident)
    const int nf = (blockIdx.x & 7) * 32 + (blockIdx.x >> 3);
    const int t0 = (nf & 15) * 256;
    const int h0 = ((nf >> 4) & 1) * 256;
    const int b  = nf >> 5;

    const char* Wt_c = (const char*)Wt;
    const char* xT_c = (const char*)xT;
    const char* zz   = (const char*)zeros;

    // ---- staging descriptors (linear LDS dst; swizzle folded into global src) ----
    const char* asrc[4]; int adst[4];
#pragma unroll
    for (int i = 0; i < 4; ++i) {
        int s = tid + i * 512;                        // 0..2047
        int kk = s >> 10, row = (s >> 2) & 255, sl = s & 3;
        int colch = (sl ^ ((row >> 1) & 3)) * 8;
        asrc[i] = Wt_c + (((size_t)(kk * Hh + h0 + row)) * Cc + colch) * 2;
        adst[i] = s * 16;
    }
    const char* bsrc[2]; int bdst[2];
#pragma unroll
    for (int i = 0; i < 2; ++i) {
        int s = tid + i * 512;                        // rows 0..255
        int row = s >> 2, sl = s & 3;
        int colch = (sl ^ ((row >> 1) & 3)) * 8;
        int tg = t0 - 3 + row;
        bsrc[i] = (tg >= 0 && tg < Tt)
                ? xT_c + (((size_t)b * Tt + tg) * Cc + colch) * 2 : zz;
        bdst[i] = s * 16;
    }
    const char* btsrc; {                              // tail rows 256..258 (+pad), const dst
        int row = 256 + (lane >> 2), sl = lane & 3;
        int colch = (sl ^ ((row >> 1) & 3)) * 8;
        int tg = t0 - 3 + row;
        btsrc = (row <= 258 && tg < Tt)
              ? xT_c + (((size_t)b * Tt + tg) * Cc + colch) * 2 : zz;
    }

    // ---- fragment read offsets (swizzled; 2-way bank aliasing only) ----
    const int aoffb = (wr * 128 + l15) * 64 + ((lg ^ ((l15 >> 1) & 3)) << 4);
    int bofftab[4];
#pragma unroll
    for (int k = 0; k < 4; ++k)
        bofftab[k] = (wc * 64 + l15 + k) * 64 + ((lg ^ (((l15 + k) >> 1) & 3)) << 4);
    const int boff0 = bofftab[0], boff1 = bofftab[1];
    const int boff2 = bofftab[2], boff3 = bofftab[3];

    f32x4 acc[8][4] = {};

    // ---- prologue: A(0) 4, B(0) 3, A(1) 4 -> vmcnt(4) keeps A(1) in flight ----
#pragma unroll
    for (int i = 0; i < 4; ++i) gload16(asrc[i], smem + adst[i]);
#pragma unroll
    for (int i = 0; i < 2; ++i) gload16(bsrc[i], smem + B_BASE + bdst[i]);
    gload16(btsrc, smem + B_BASE + 16384);
#pragma unroll
    for (int i = 0; i < 4; ++i) gload16(asrc[i] + 524288, smem + A_STRIDE + adst[i]);
    asm volatile("s_waitcnt vmcnt(4)" ::: "memory");
    BAR;

    // ---- main loop: 16 K-steps x 4 phases ----
#pragma unroll
    for (int s = 0; s < 16; ++s) {
        const char* Ab  = smem + (s % 3) * A_STRIDE;
        const char* Bbf = smem + B_BASE + ((s >> 1) & 1) * B_STRIDE;
        char* And = smem + ((s + 2) % 3) * A_STRIDE;
        char* Bnd = smem + B_BASE + (((s >> 1) + 1) & 1) * B_STRIDE;
        const bool doA = (s + 2) <= 15;
        const bool doB = ((s & 1) == 0) && ((s >> 1) + 1 <= 7);
        const long aadv = (long)((s + 2) & 1) * 524288 + (long)((s + 2) >> 1) * 64;
        const int  badv = ((s >> 1) + 1) * 64;
        const int  bo0 = (s & 1) ? boff2 : boff0;     // conv-k = kb+0
        const int  bo1 = (s & 1) ? boff3 : boff1;     // conv-k = kb+1

        bf16x8 a_[4], b_[4];
        // -- P0: A fm0-3 ks0 + B slice0 --
#pragma unroll
        for (int fm = 0; fm < 4; ++fm) a_[fm] = *(const bf16x8*)(Ab + aoffb + fm * 1024);
#pragma unroll
        for (int ft = 0; ft < 4; ++ft) b_[ft] = *(const bf16x8*)(Bbf + bo0 + ft * 1024);
        if (doA) { gload16(asrc[0] + aadv, And + adst[0]); gload16(asrc[1] + aadv, And + adst[1]); }
        BAR; LGKM0;
        __builtin_amdgcn_s_setprio(1);
#pragma unroll
        for (int fm = 0; fm < 4; ++fm)
#pragma unroll
            for (int ft = 0; ft < 4; ++ft)
                acc[fm][ft] = __builtin_amdgcn_mfma_f32_16x16x32_bf16(a_[fm], b_[ft], acc[fm][ft], 0, 0, 0);
        __builtin_amdgcn_s_setprio(0);
        BAR;
        // -- P1: A fm4-7 ks0 (reuses b_) --
#pragma unroll
        for (int fm = 0; fm < 4; ++fm) a_[fm] = *(const bf16x8*)(Ab + aoffb + (fm + 4) * 1024);
        if (doA) { gload16(asrc[2] + aadv, And + adst[2]); gload16(asrc[3] + aadv, And + adst[3]); }
        BAR; LGKM0;
        __builtin_amdgcn_s_setprio(1);
#pragma unroll
        for (int fm = 0; fm < 4; ++fm)
#pragma unroll
            for (int ft = 0; ft < 4; ++ft)
                acc[fm + 4][ft] = __builtin_amdgcn_mfma_f32_16x16x32_bf16(a_[fm], b_[ft], acc[fm + 4][ft], 0, 0, 0);
        __builtin_amdgcn_s_setprio(0);
        BAR;
        // -- P2: A fm0-3 ks1 + B slice1 --
#pragma unroll
        for (int fm = 0; fm < 4; ++fm) a_[fm] = *(const bf16x8*)(Ab + 16384 + aoffb + fm * 1024);
#pragma unroll
        for (int ft = 0; ft < 4; ++ft) b_[ft] = *(const bf16x8*)(Bbf + bo1 + ft * 1024);
        if (doB) { gload16(bsrc[0] + badv, Bnd + bdst[0]); gload16(bsrc[1] + badv, Bnd + bdst[1]); }
        BAR; LGKM0;
        __builtin_amdgcn_s_setprio(1);
#pragma unroll
        for (int fm = 0; fm < 4; ++fm)
#pragma unroll
            for (int ft = 0; ft < 4; ++ft)
                acc[fm][ft] = __builtin_amdgcn_mfma_f32_16x16x32_bf16(a_[fm], b_[ft], acc[fm][ft], 0, 0, 0);
        __builtin_amdgcn_s_setprio(0);
        BAR;
        // -- P3: A fm4-7 ks1 --
#pragma unroll
        for (int fm = 0; fm < 4; ++fm) a_[fm] = *(const bf16x8*)(Ab + 16384 + aoffb + (fm + 4) * 1024);
        if (doB) gload16(btsrc + badv, Bnd + 16384);
        BAR; LGKM0;
        __builtin_amdgcn_s_setprio(1);
#pragma unroll
        for (int fm = 0; fm < 4; ++fm)
#pragma unroll
            for (int ft = 0; ft < 4; ++ft)
                acc[fm + 4][ft] = __builtin_amdgcn_mfma_f32_16x16x32_bf16(a_[fm], b_[ft], acc[fm + 4][ft], 0, 0, 0);
        __builtin_amdgcn_s_setprio(0);
        // counted vmcnt, once per K-step (never 0 in steady state)
        if (s < 14) {
            if ((s & 1) == 0) asm volatile("s_waitcnt vmcnt(7)" ::: "memory");
            else              asm volatile("s_waitcnt vmcnt(4)" ::: "memory");
        } else if (s == 14)   asm volatile("s_waitcnt vmcnt(0)" ::: "memory");
        BAR;
    }

    // ---- epilogue: D col=l15 -> t, row=lg*4+q -> h ----
#pragma unroll
    for (int fm = 0; fm < 8; ++fm) {
        int hb = h0 + wr * 128 + fm * 16 + lg * 4;
        float4 bs = *(const float4*)&bias[hb];
        const float* bsp = (const float*)&bs;
#pragma unroll
        for (int q = 0; q < 4; ++q)
#pragma unroll
            for (int ft = 0; ft < 4; ++ft) {
                int t = t0 + wc * 64 + ft * 16 + l15;
                out[((size_t)(b * Hh + hb + q)) * Tt + t] = acc[fm][ft][q] + bsp[q];
            }
    }
}

// ---------------- fallback (ws too small): fp32 kernel ----------------
#define TT 256
#define HT 8
#define CT 4
__global__ __launch_bounds__(256) void conv1d_f32_kernel(
    const float* __restrict__ x, const float* __restrict__ W,
    const float* __restrict__ bias, float* __restrict__ out)
{
    const int tid = threadIdx.x;
    const int t0 = blockIdx.x * TT;
    const int h0 = blockIdx.y * HT;
    const int b  = blockIdx.z;
    __shared__ float xs[CT][TT + Kk];
    float acc[HT];
#pragma unroll
    for (int h = 0; h < HT; ++h) acc[h] = 0.f;
    const float* xb = x + (size_t)b * Cc * Tt;
    for (int c0 = 0; c0 < Cc; c0 += CT) {
        __syncthreads();
#pragma unroll
        for (int cc = 0; cc < CT; ++cc)
            for (int j = tid; j < TT + Kk - 1; j += 256) {
                int idx = t0 - (Kk - 1) + j;
                xs[cc][j] = (idx >= 0) ? xb[(size_t)(c0 + cc) * Tt + idx] : 0.f;
            }
        __syncthreads();
#pragma unroll
        for (int cc = 0; cc < CT; ++cc) {
            float xv[Kk];
#pragma unroll
            for (int k = 0; k < Kk; ++k) xv[k] = xs[cc][tid + k];
#pragma unroll
            for (int h = 0; h < HT; ++h) {
                const float* wp = W + (size_t)(h0 + h) * (Cc * Kk) + (size_t)(c0 + cc) * Kk;
#pragma unroll
                for (int k = 0; k < Kk; ++k) acc[h] += wp[k] * xv[k];
            }
        }
    }
#pragma unroll
    for (int h = 0; h < HT; ++h)
        out[((size_t)b * Hh + (h0 + h)) * Tt + t0 + tid] = acc[h] + bias[h0 + h];
}

extern "C" void kernel_launch(void* const* d_in, const int* in_sizes, int n_in,
                              void* d_out, int out_size, void* d_ws, size_t ws_size,
                              hipStream_t stream) {
    const float* x    = (const float*)d_in[0];
    const float* W    = (const float*)d_in[1];
    const float* bias = (const float*)d_in[2];
    float* out        = (float*)d_out;

    if (ws_size >= WS_NEEDED) {
        __hip_bfloat16* xT = (__hip_bfloat16*)((char*)d_ws + WS_XT_OFF);
        __hip_bfloat16* Wt = (__hip_bfloat16*)((char*)d_ws + WS_WT_OFF);
        float* zeros       = (float*)((char*)d_ws + WS_ZERO_OFF);

        prep_kernel<<<dim3(4096), dim3(256), 0, stream>>>(x, W, xT, Wt, zeros);
        conv_mfma_kernel<<<dim3(256), dim3(512), 0, stream>>>(xT, Wt, bias, zeros, out);
    } else {
        conv1d_f32_kernel<<<dim3(Tt / TT, Hh / HT, Bb), dim3(256), 0, stream>>>(x, W, bias, out);
    }
}